// Round 1
// baseline (18244.072 us; speedup 1.0000x reference)
//
#include <hip/hip_runtime.h>

// GromovWasserstein — fp32-exact fused kernel.
// One 512-thread workgroup per batch (bs=2048, n=128). X resident in LDS,
// Y/Y2/C in registers, Sinkhorn register-resident. No half precision anywhere:
// the iteration amplifies rounding noise ~1e4x, so C must be computed in fp32.
//
// R1 change: LDS (138 KB) limits residency to 1 block/CU = 2 waves/SIMD, so a
// VGPR budget of 256/wave is free. The previous __launch_bounds__(512, 2)
// caused the allocator to budget 128 VGPRs/wave; the stage-2 live set
// (Yv+Y2v+Cv+yv+y2v ~190 floats) spilled to scratch -> 8.3 GB of HBM writes
// per dispatch (vs 134 MB of actual output). Pin waves/EU to exactly 2 and
// let the allocator use up to 256 VGPRs: spills eliminated, occupancy
// unchanged.

typedef float f4 __attribute__((ext_vector_type(4)));

#define NTHR 512

__global__ __launch_bounds__(512)
__attribute__((amdgpu_waves_per_eu(2, 2)))
void gw32(
    const float* __restrict__ Xg, const float* __restrict__ F1g,
    const float* __restrict__ F2g, const float* __restrict__ Kpg,
    float* __restrict__ Og)
{
    // XS: X resident [128][132] (stride 132: b128-aligned rows).    67,584 B
    // SH2: time-multiplexed region (F2 tiles | Y/Y2+F1 tiles | Xe). 69,632 B
    __shared__ __align__(16) float XS[128 * 132];
    __shared__ __align__(16) float SH2[17408];
    __shared__ __align__(16) float luS[128];
    __shared__ __align__(16) float rvS[128];
    __shared__ float wred[8];

    const int tid = threadIdx.x;
    const size_t base = (size_t)blockIdx.x << 14;
    const float* Xp  = Xg  + base;
    const float* F1p = F1g + base;
    const float* F2p = F2g + base;
    const float* Kpp = Kpg + base;
    float* Op = Og + base;

    // matmul-phase mapping: thread owns column j, row-quarter q (rows q*32..+32)
    const int j = tid & 127;
    const int q = tid >> 7;
    // sinkhorn-phase mapping: si = row (row phase) / col (col phase), sq = quarter
    const int si = tid >> 2;
    const int sq = tid & 3;

    float* F2S  = SH2;            // [64][128]  F2 row-panel
    float* F2TS = SH2 + 8192;     // [64][129]  F2 col-panel (transposed, padded)
    float* YT   = SH2;            // [32][128]  Y k-tile
    float* Y2T  = SH2 + 4096;     // [32][128]  Y2 k-tile
    float* F1CT = SH2 + 8192;     // [128][36]  F1[i][ktile]  (i-major)
    float* F1RT = SH2 + 12800;    // [128][36]  F1[ktile][i] transposed (i-major)
    float* ES   = SH2;            // [128][132] Xe

    // load X (fp32, resident)
    for (int e = tid; e < 16384; e += NTHR)
        XS[(e >> 7) * 132 + (e & 127)] = Xp[e];
    __syncthreads();

#pragma unroll 1
    for (int it = 0; it < 15; ++it) {
        // ---------------- stage 1: Y = X*F2, Y2 = X*F2^T (registers) ----------------
        float Yv[32], Y2v[32];
#pragma unroll
        for (int k = 0; k < 32; ++k) { Yv[k] = 0.f; Y2v[k] = 0.f; }

#pragma unroll 1
        for (int mh = 0; mh < 2; ++mh) {
            __syncthreads();  // SH2 reuse guard
            for (int e = tid; e < 8192; e += NTHR) {
                F2S[(e >> 7) * 128 + (e & 127)] =
                    F2p[((mh << 6) + (e >> 7)) * 128 + (e & 127)];
                F2TS[(e & 63) * 129 + (e >> 6)] =
                    F2p[(e >> 6) * 128 + (mh << 6) + (e & 63)];
            }
            __syncthreads();
#pragma unroll 1
            for (int m4 = 0; m4 < 16; ++m4) {
                const int mm = m4 * 4;
                float fr[4], ft[4];
#pragma unroll
                for (int u = 0; u < 4; ++u) {
                    fr[u] = F2S[(mm + u) * 128 + j];
                    ft[u] = F2TS[(mm + u) * 129 + j];
                }
#pragma unroll
                for (int k = 0; k < 32; ++k) {
                    f4 x = *(const f4*)&XS[(q * 32 + k) * 132 + (mh << 6) + mm];
                    Yv[k]  += x[0]*fr[0] + x[1]*fr[1] + x[2]*fr[2] + x[3]*fr[3];
                    Y2v[k] += x[0]*ft[0] + x[1]*ft[1] + x[2]*ft[2] + x[3]*ft[3];
                }
            }
        }

        // ---------------- stage 2: C = Kp + F1*Y + F1^T*Y2 (registers) ----------------
        float Cv[32];
#pragma unroll
        for (int ii = 0; ii < 32; ++ii)
            Cv[ii] = Kpp[(q * 32 + ii) * 128 + j];

#pragma unroll 1
        for (int kt = 0; kt < 4; ++kt) {
            __syncthreads();  // protect prior tile reads / stage-1 reads
            if (q == kt) {
#pragma unroll
                for (int kk = 0; kk < 32; ++kk) {
                    YT[kk * 128 + j]  = Yv[kk];
                    Y2T[kk * 128 + j] = Y2v[kk];
                }
            }
            for (int e = tid; e < 4096; e += NTHR) {
                F1CT[(e >> 5) * 36 + (e & 31)] =
                    F1p[(e >> 5) * 128 + kt * 32 + (e & 31)];
                F1RT[(e & 127) * 36 + (e >> 7)] =
                    F1p[(kt * 32 + (e >> 7)) * 128 + (e & 127)];
            }
            __syncthreads();

            float yv[32], y2v[32];
#pragma unroll
            for (int kk = 0; kk < 32; ++kk) {
                yv[kk]  = YT[kk * 128 + j];
                y2v[kk] = Y2T[kk * 128 + j];
            }
#pragma unroll
            for (int ii = 0; ii < 32; ++ii) {
                float c = Cv[ii];
                const int i = q * 32 + ii;
#pragma unroll
                for (int k4 = 0; k4 < 8; ++k4) {
                    f4 a = *(const f4*)&F1CT[i * 36 + k4 * 4];  // F1[i][k']
                    f4 b = *(const f4*)&F1RT[i * 36 + k4 * 4];  // F1[k'][i]
                    c += a[0]*yv[k4*4+0] + a[1]*yv[k4*4+1]
                       + a[2]*yv[k4*4+2] + a[3]*yv[k4*4+3]
                       + b[0]*y2v[k4*4+0] + b[1]*y2v[k4*4+1]
                       + b[2]*y2v[k4*4+2] + b[3]*y2v[k4*4+3];
                }
                Cv[ii] = c;
            }
        }

        // ---------------- norm = max|C|, Xe = exp2(C * 10*log2(e)/norm) ----------------
        float mx = 0.f;
#pragma unroll
        for (int ii = 0; ii < 32; ++ii) mx = fmaxf(mx, fabsf(Cv[ii]));
#pragma unroll
        for (int off = 1; off < 64; off <<= 1)
            mx = fmaxf(mx, __shfl_xor(mx, off, 64));
        if ((tid & 63) == 0) wred[tid >> 6] = mx;
        __syncthreads();   // also separates F1/Y tile reads from ES overwrite
        float nrm = wred[0];
#pragma unroll
        for (int u = 1; u < 8; ++u) nrm = fmaxf(nrm, wred[u]);
        const float se = 14.426950408889634f / nrm;  // 10*log2(e)/norm

#pragma unroll
        for (int ii = 0; ii < 32; ++ii)
            ES[(q * 32 + ii) * 132 + j] = exp2f(Cv[ii] * se);
        if (tid < 128) rvS[tid] = 1.0f;
        __syncthreads();

        // register copies: xer = row si (cols sq*32..+32); xec = col si (rows sq*32..+32)
        f4 xer[8];
        float xec[32];
#pragma unroll
        for (int u = 0; u < 8; ++u)
            xer[u] = *(const f4*)&ES[si * 132 + sq * 32 + u * 4];
#pragma unroll
        for (int ii = 0; ii < 32; ++ii)
            xec[ii] = ES[(sq * 32 + ii) * 132 + si];

        // ---------------- Sinkhorn: lu = 1/(Xe rv); rv = min(1/(Xe^T lu), 1) ----------------
        float lu = 0.f;
#pragma unroll 1
        for (int sit = 0; sit < 15; ++sit) {
            f4 s4 = {0.f, 0.f, 0.f, 0.f};
#pragma unroll
            for (int u = 0; u < 8; ++u) {
                f4 rv4 = *(const f4*)&rvS[sq * 32 + u * 4];
                s4 += xer[u] * rv4;
            }
            float s = (s4[0] + s4[1]) + (s4[2] + s4[3]);
            s += __shfl_xor(s, 1, 64);
            s += __shfl_xor(s, 2, 64);
            lu = 1.0f / s;
            if (sq == 0) luS[si] = lu;
            __syncthreads();

            f4 t4 = {0.f, 0.f, 0.f, 0.f};
#pragma unroll
            for (int u = 0; u < 8; ++u) {
                f4 lu4 = *(const f4*)&luS[sq * 32 + u * 4];
                f4 xc4 = { xec[u*4+0], xec[u*4+1], xec[u*4+2], xec[u*4+3] };
                t4 += xc4 * lu4;
            }
            float s2 = (t4[0] + t4[1]) + (t4[2] + t4[3]);
            s2 += __shfl_xor(s2, 1, 64);
            s2 += __shfl_xor(s2, 2, 64);
            float rv = fminf(1.0f / s2, 1.0f);
            if (sq == 0) rvS[si] = rv;
            __syncthreads();
        }

        // ---------------- X = lu * Xe * rv^T ----------------
        if (it < 14) {
#pragma unroll
            for (int u = 0; u < 8; ++u) {
                f4 rv4 = *(const f4*)&rvS[sq * 32 + u * 4];
                f4 xv = xer[u] * lu * rv4;
                *(f4*)&XS[si * 132 + sq * 32 + u * 4] = xv;
            }
        } else {
#pragma unroll
            for (int u = 0; u < 8; ++u) {
                f4 rv4 = *(const f4*)&rvS[sq * 32 + u * 4];
                f4 xv = xer[u] * lu * rv4;
                *(f4*)&Op[si * 128 + sq * 32 + u * 4] = xv;
            }
        }
        __syncthreads();
    }
}

extern "C" void kernel_launch(void* const* d_in, const int* in_sizes, int n_in,
                              void* d_out, int out_size, void* d_ws, size_t ws_size,
                              hipStream_t stream) {
    const float* X  = (const float*)d_in[0];
    const float* F1 = (const float*)d_in[1];
    const float* F2 = (const float*)d_in[2];
    const float* Kp = (const float*)d_in[3];
    float* out = (float*)d_out;
    int bs = in_sizes[0] >> 14;  // elements / (128*128)
    gw32<<<bs, NTHR, 0, stream>>>(X, F1, F2, Kp, out);
}

// Round 2
// 16793.005 us; speedup vs baseline: 1.0864x; 1.0864x over previous
//
#include <hip/hip_runtime.h>

// GromovWasserstein — fp32-exact fused kernel.
// One 512-thread workgroup per batch (bs=2048, n=128). X resident in LDS,
// C in registers, Sinkhorn register-resident. No half precision anywhere:
// the iteration amplifies rounding noise ~1e4x, so C must be computed in fp32.
//
// R2 change: the old single-pass stage 2 held Cv[32]+Yv[32]+Y2v[32]+yv[32]+
// y2v[32] = 160 live floats against a 128-VGPR allocation -> forced spills
// (8.9 GB of scratch HBM writes per dispatch vs 134 MB of output; 49% VALU).
// Restructured into two sequential passes over the resident X:
//   pass A: Yv = X*F2   (regs), then Cv = Kp + F1*Y    (kt-tiled via LDS)
//   pass B: Y2v = X*F2t (regs), then Cv += F1t*Y2      (kt-tiled via LDS)
// Peak live set is now Cv+Yv+yv = 96 floats -> fits 128 VGPRs, no scratch.
// Global traffic unchanged (F1,F2 each read twice/iter, Kp once — same as
// before); FMA count unchanged. Bonus: F2 and F2t no longer need to coexist
// in LDS, so each pass stages the full 128x128 panel once (no mh halving).

typedef float f4 __attribute__((ext_vector_type(4)));

#define NTHR 512

__global__ __launch_bounds__(512, 2) void gw32(
    const float* __restrict__ Xg, const float* __restrict__ F1g,
    const float* __restrict__ F2g, const float* __restrict__ Kpg,
    float* __restrict__ Og)
{
    // XS: X resident [128][132] (stride 132: b128-aligned rows).    67,584 B
    // SH2: time-multiplexed region (F2 panel | Y tile + F1 tile | Xe). 69,632 B
    __shared__ __align__(16) float XS[128 * 132];
    __shared__ __align__(16) float SH2[17408];
    __shared__ __align__(16) float luS[128];
    __shared__ __align__(16) float rvS[128];
    __shared__ float wred[8];

    const int tid = threadIdx.x;
    const size_t base = (size_t)blockIdx.x << 14;
    const float* Xp  = Xg  + base;
    const float* F1p = F1g + base;
    const float* F2p = F2g + base;
    const float* Kpp = Kpg + base;
    float* Op = Og + base;

    // matmul-phase mapping: thread owns column j, row-quarter q (rows q*32..+32)
    const int j = tid & 127;
    const int q = tid >> 7;
    // sinkhorn-phase mapping: si = row (row phase) / col (col phase), sq = quarter
    const int si = tid >> 2;
    const int sq = tid & 3;

    float* F2S  = SH2;            // [128][128] F2 full panel       (pass A)
    float* F2TS = SH2;            // [128][129] F2^T full panel     (pass B)
    float* YT   = SH2;            // [32][128]  Y / Y2 k-tile       (per kt)
    float* F1T  = SH2 + 8192;     // [128][36]  F1 tile, i-major    (per kt)
    float* ES   = SH2;            // [128][132] Xe

    // load X (fp32, resident)
    for (int e = tid; e < 16384; e += NTHR)
        XS[(e >> 7) * 132 + (e & 127)] = Xp[e];
    __syncthreads();

#pragma unroll 1
    for (int it = 0; it < 15; ++it) {
        float Cv[32];
#pragma unroll
        for (int ii = 0; ii < 32; ++ii)
            Cv[ii] = Kpp[(q * 32 + ii) * 128 + j];

        // ================= pass A: Y = X*F2, Cv += F1*Y =================
        {
            float Yv[32];
#pragma unroll
            for (int k = 0; k < 32; ++k) Yv[k] = 0.f;

            __syncthreads();  // SH2 reuse guard
            for (int e = tid; e < 16384; e += NTHR)
                F2S[e] = F2p[e];
            __syncthreads();

#pragma unroll 1
            for (int m4 = 0; m4 < 32; ++m4) {
                const int mm = m4 * 4;
                float fr[4];
#pragma unroll
                for (int u = 0; u < 4; ++u)
                    fr[u] = F2S[(mm + u) * 128 + j];
#pragma unroll
                for (int k = 0; k < 32; ++k) {
                    f4 x = *(const f4*)&XS[(q * 32 + k) * 132 + mm];
                    Yv[k] += x[0]*fr[0] + x[1]*fr[1] + x[2]*fr[2] + x[3]*fr[3];
                }
            }

            // Cv += F1 * Y, kt-tiled: F1T[i][k'] = F1[i][kt*32+k']
#pragma unroll 1
            for (int kt = 0; kt < 4; ++kt) {
                __syncthreads();  // protect prior tile reads / F2S reads
                if (q == kt) {
#pragma unroll
                    for (int kk = 0; kk < 32; ++kk)
                        YT[kk * 128 + j] = Yv[kk];
                }
                for (int e = tid; e < 4096; e += NTHR)
                    F1T[(e >> 5) * 36 + (e & 31)] =
                        F1p[(e >> 5) * 128 + kt * 32 + (e & 31)];
                __syncthreads();

                float yv[32];
#pragma unroll
                for (int kk = 0; kk < 32; ++kk)
                    yv[kk] = YT[kk * 128 + j];
#pragma unroll
                for (int ii = 0; ii < 32; ++ii) {
                    float c = Cv[ii];
                    const int i = q * 32 + ii;
#pragma unroll
                    for (int k4 = 0; k4 < 8; ++k4) {
                        f4 a = *(const f4*)&F1T[i * 36 + k4 * 4];  // F1[i][k']
                        c += a[0]*yv[k4*4+0] + a[1]*yv[k4*4+1]
                           + a[2]*yv[k4*4+2] + a[3]*yv[k4*4+3];
                    }
                    Cv[ii] = c;
                }
            }
        }

        // ================= pass B: Y2 = X*F2^T, Cv += F1^T*Y2 =================
        {
            float Y2v[32];
#pragma unroll
            for (int k = 0; k < 32; ++k) Y2v[k] = 0.f;

            __syncthreads();  // SH2 reuse guard
            for (int e = tid; e < 16384; e += NTHR)
                F2TS[(e & 127) * 129 + (e >> 7)] = F2p[e];  // F2TS[m][j] = F2[j][m]
            __syncthreads();

#pragma unroll 1
            for (int m4 = 0; m4 < 32; ++m4) {
                const int mm = m4 * 4;
                float ft[4];
#pragma unroll
                for (int u = 0; u < 4; ++u)
                    ft[u] = F2TS[(mm + u) * 129 + j];
#pragma unroll
                for (int k = 0; k < 32; ++k) {
                    f4 x = *(const f4*)&XS[(q * 32 + k) * 132 + mm];
                    Y2v[k] += x[0]*ft[0] + x[1]*ft[1] + x[2]*ft[2] + x[3]*ft[3];
                }
            }

            // Cv += F1^T * Y2, kt-tiled: F1T[i][k'] = F1[kt*32+k'][i]
#pragma unroll 1
            for (int kt = 0; kt < 4; ++kt) {
                __syncthreads();
                if (q == kt) {
#pragma unroll
                    for (int kk = 0; kk < 32; ++kk)
                        YT[kk * 128 + j] = Y2v[kk];
                }
                for (int e = tid; e < 4096; e += NTHR)
                    F1T[(e & 127) * 36 + (e >> 7)] =
                        F1p[(kt * 32 + (e >> 7)) * 128 + (e & 127)];
                __syncthreads();

                float y2v[32];
#pragma unroll
                for (int kk = 0; kk < 32; ++kk)
                    y2v[kk] = YT[kk * 128 + j];
#pragma unroll
                for (int ii = 0; ii < 32; ++ii) {
                    float c = Cv[ii];
                    const int i = q * 32 + ii;
#pragma unroll
                    for (int k4 = 0; k4 < 8; ++k4) {
                        f4 b = *(const f4*)&F1T[i * 36 + k4 * 4];  // F1[k'][i]
                        c += b[0]*y2v[k4*4+0] + b[1]*y2v[k4*4+1]
                           + b[2]*y2v[k4*4+2] + b[3]*y2v[k4*4+3];
                    }
                    Cv[ii] = c;
                }
            }
        }

        // ---------------- norm = max|C|, Xe = exp2(C * 10*log2(e)/norm) ----------------
        float mx = 0.f;
#pragma unroll
        for (int ii = 0; ii < 32; ++ii) mx = fmaxf(mx, fabsf(Cv[ii]));
#pragma unroll
        for (int off = 1; off < 64; off <<= 1)
            mx = fmaxf(mx, __shfl_xor(mx, off, 64));
        if ((tid & 63) == 0) wred[tid >> 6] = mx;
        __syncthreads();   // also separates F1/Y tile reads from ES overwrite
        float nrm = wred[0];
#pragma unroll
        for (int u = 1; u < 8; ++u) nrm = fmaxf(nrm, wred[u]);
        const float se = 14.426950408889634f / nrm;  // 10*log2(e)/norm

#pragma unroll
        for (int ii = 0; ii < 32; ++ii)
            ES[(q * 32 + ii) * 132 + j] = exp2f(Cv[ii] * se);
        if (tid < 128) rvS[tid] = 1.0f;
        __syncthreads();

        // register copies: xer = row si (cols sq*32..+32); xec = col si (rows sq*32..+32)
        f4 xer[8];
        float xec[32];
#pragma unroll
        for (int u = 0; u < 8; ++u)
            xer[u] = *(const f4*)&ES[si * 132 + sq * 32 + u * 4];
#pragma unroll
        for (int ii = 0; ii < 32; ++ii)
            xec[ii] = ES[(sq * 32 + ii) * 132 + si];

        // ---------------- Sinkhorn: lu = 1/(Xe rv); rv = min(1/(Xe^T lu), 1) ----------------
        float lu = 0.f;
#pragma unroll 1
        for (int sit = 0; sit < 15; ++sit) {
            f4 s4 = {0.f, 0.f, 0.f, 0.f};
#pragma unroll
            for (int u = 0; u < 8; ++u) {
                f4 rv4 = *(const f4*)&rvS[sq * 32 + u * 4];
                s4 += xer[u] * rv4;
            }
            float s = (s4[0] + s4[1]) + (s4[2] + s4[3]);
            s += __shfl_xor(s, 1, 64);
            s += __shfl_xor(s, 2, 64);
            lu = 1.0f / s;
            if (sq == 0) luS[si] = lu;
            __syncthreads();

            f4 t4 = {0.f, 0.f, 0.f, 0.f};
#pragma unroll
            for (int u = 0; u < 8; ++u) {
                f4 lu4 = *(const f4*)&luS[sq * 32 + u * 4];
                f4 xc4 = { xec[u*4+0], xec[u*4+1], xec[u*4+2], xec[u*4+3] };
                t4 += xc4 * lu4;
            }
            float s2 = (t4[0] + t4[1]) + (t4[2] + t4[3]);
            s2 += __shfl_xor(s2, 1, 64);
            s2 += __shfl_xor(s2, 2, 64);
            float rv = fminf(1.0f / s2, 1.0f);
            if (sq == 0) rvS[si] = rv;
            __syncthreads();
        }

        // ---------------- X = lu * Xe * rv^T ----------------
        if (it < 14) {
#pragma unroll
            for (int u = 0; u < 8; ++u) {
                f4 rv4 = *(const f4*)&rvS[sq * 32 + u * 4];
                f4 xv = xer[u] * lu * rv4;
                *(f4*)&XS[si * 132 + sq * 32 + u * 4] = xv;
            }
        } else {
#pragma unroll
            for (int u = 0; u < 8; ++u) {
                f4 rv4 = *(const f4*)&rvS[sq * 32 + u * 4];
                f4 xv = xer[u] * lu * rv4;
                *(f4*)&Op[si * 128 + sq * 32 + u * 4] = xv;
            }
        }
        __syncthreads();
    }
}

extern "C" void kernel_launch(void* const* d_in, const int* in_sizes, int n_in,
                              void* d_out, int out_size, void* d_ws, size_t ws_size,
                              hipStream_t stream) {
    const float* X  = (const float*)d_in[0];
    const float* F1 = (const float*)d_in[1];
    const float* F2 = (const float*)d_in[2];
    const float* Kp = (const float*)d_in[3];
    float* out = (float*)d_out;
    int bs = in_sizes[0] >> 14;  // elements / (128*128)
    gw32<<<bs, NTHR, 0, stream>>>(X, F1, F2, Kp, out);
}

// Round 3
// 9522.507 us; speedup vs baseline: 1.9159x; 1.7635x over previous
//
#include <hip/hip_runtime.h>

// GromovWasserstein — fp32-exact fused kernel.
// One 512-thread workgroup per batch (bs=2048, n=128). X resident in LDS,
// C in registers, Sinkhorn register-resident. No half precision anywhere.
//
// R3 change: R2 killed the register spills (WRITE_SIZE 8.7e6 -> 1.76e5 KB)
// but dur only moved 18.2 -> 16.9 ms: the kernel is issue/stall-bound.
// Audit: (a) each ds_read_b128 of X fed only 4 FMAs (1 output column per
// thread) -> 4336 b128/thread/iter, LDS pipe ~4 ms and constant load-use
// stalls; (b) accumulations written as sum-trees contract to ~6 VALU per
// 4 MACs instead of 4 FMA.
// Fix: 2D register blocking — each thread owns an 8-row x 4-col (f4) tile of
// Y/C. Per m4 step: 12 LDS reads feed 128 FMAs (was 33). All accumulations
// are single-statement `acc += vec * scalar` -> pure v_fma_f32 chains.
// F2^T panel stride 129 -> 132 so its f4 reads stay 16B-aligned (the
// transposed scalar stores become 8-way bank-conflicted, but that's only
// 32 stores/thread/iter — bounded ~0.1 ms).
// Barrier structure, Sinkhorn phase, and LDS footprint unchanged from R2.

typedef float f4 __attribute__((ext_vector_type(4)));

#define NTHR 512

__global__ __launch_bounds__(512, 2) void gw32(
    const float* __restrict__ Xg, const float* __restrict__ F1g,
    const float* __restrict__ F2g, const float* __restrict__ Kpg,
    float* __restrict__ Og)
{
    // XS: X resident [128][132] (stride 132: b128-aligned rows).    67,584 B
    // SH2: time-multiplexed (F2 panel | F2T panel | Y+F1 tiles | Xe). 69,632 B
    __shared__ __align__(16) float XS[128 * 132];
    __shared__ __align__(16) float SH2[17408];
    __shared__ __align__(16) float luS[128];
    __shared__ __align__(16) float rvS[128];
    __shared__ float wred[8];

    const int tid = threadIdx.x;
    const size_t base = (size_t)blockIdx.x << 14;
    const float* Xp  = Xg  + base;
    const float* F1p = F1g + base;
    const float* F2p = F2g + base;
    const float* Kpp = Kpg + base;
    float* Op = Og + base;

    // matmul-phase mapping: thread owns rows r0..r0+7, cols cq..cq+3 (f4)
    const int jj = tid & 31;
    const int cq = jj << 2;
    const int ww = tid >> 5;
    const int r0 = ww << 3;
    // sinkhorn-phase mapping: si = row (row phase) / col (col phase), sq = quarter
    const int si = tid >> 2;
    const int sq = tid & 3;

    float* F2S  = SH2;            // [128][128] F2 full panel       (pass A)
    float* F2TS = SH2;            // [128][132] F2^T full panel     (pass B)
    float* YT   = SH2;            // [32][128]  Y / Y2 k-tile       (per kt)
    float* F1T  = SH2 + 8192;     // [128][36]  F1 tile, i-major    (per kt)
    float* ES   = SH2;            // [128][132] Xe

    // load X (fp32, resident), f4
    for (int e = tid; e < 4096; e += NTHR)
        *(f4*)&XS[(e >> 5) * 132 + ((e & 31) << 2)] = *(const f4*)&Xp[e << 2];
    __syncthreads();

#pragma unroll 1
    for (int it = 0; it < 15; ++it) {
        f4 Cv[8];
#pragma unroll
        for (int r = 0; r < 8; ++r)
            Cv[r] = *(const f4*)&Kpp[(r0 + r) * 128 + cq];

        // ================= pass A: Y = X*F2, Cv += F1*Y =================
        {
            f4 Yv[8];
#pragma unroll
            for (int r = 0; r < 8; ++r) Yv[r] = (f4){0.f, 0.f, 0.f, 0.f};

            __syncthreads();  // SH2 reuse guard
            for (int e = tid; e < 4096; e += NTHR)
                *(f4*)&F2S[e << 2] = *(const f4*)&F2p[e << 2];
            __syncthreads();

#pragma unroll 1
            for (int m4 = 0; m4 < 32; ++m4) {
                const int mm = m4 << 2;
                f4 fr0 = *(const f4*)&F2S[(mm + 0) * 128 + cq];
                f4 fr1 = *(const f4*)&F2S[(mm + 1) * 128 + cq];
                f4 fr2 = *(const f4*)&F2S[(mm + 2) * 128 + cq];
                f4 fr3 = *(const f4*)&F2S[(mm + 3) * 128 + cq];
#pragma unroll
                for (int r = 0; r < 8; ++r) {
                    f4 x = *(const f4*)&XS[(r0 + r) * 132 + mm];
                    Yv[r] += fr0 * x[0];
                    Yv[r] += fr1 * x[1];
                    Yv[r] += fr2 * x[2];
                    Yv[r] += fr3 * x[3];
                }
            }

            // Cv += F1 * Y, kt-tiled: F1T[i][k'] = F1[i][kt*32+k']
#pragma unroll 1
            for (int kt = 0; kt < 4; ++kt) {
                __syncthreads();  // protect prior tile reads / F2S reads
                if ((ww >> 2) == kt) {
#pragma unroll
                    for (int r = 0; r < 8; ++r)
                        *(f4*)&YT[(((ww & 3) << 3) + r) * 128 + cq] = Yv[r];
                }
                for (int e = tid; e < 4096; e += NTHR)
                    F1T[(e >> 5) * 36 + (e & 31)] =
                        F1p[(e >> 5) * 128 + (kt << 5) + (e & 31)];
                __syncthreads();

#pragma unroll 1
                for (int k4 = 0; k4 < 8; ++k4) {
                    f4 y0 = *(const f4*)&YT[(k4 * 4 + 0) * 128 + cq];
                    f4 y1 = *(const f4*)&YT[(k4 * 4 + 1) * 128 + cq];
                    f4 y2 = *(const f4*)&YT[(k4 * 4 + 2) * 128 + cq];
                    f4 y3 = *(const f4*)&YT[(k4 * 4 + 3) * 128 + cq];
#pragma unroll
                    for (int r = 0; r < 8; ++r) {
                        f4 a = *(const f4*)&F1T[(r0 + r) * 36 + (k4 << 2)];
                        Cv[r] += y0 * a[0];
                        Cv[r] += y1 * a[1];
                        Cv[r] += y2 * a[2];
                        Cv[r] += y3 * a[3];
                    }
                }
            }
        }

        // ================= pass B: Y2 = X*F2^T, Cv += F1^T*Y2 =================
        {
            f4 Yv[8];
#pragma unroll
            for (int r = 0; r < 8; ++r) Yv[r] = (f4){0.f, 0.f, 0.f, 0.f};

            __syncthreads();  // SH2 reuse guard
            for (int e = tid; e < 16384; e += NTHR)
                F2TS[(e & 127) * 132 + (e >> 7)] = F2p[e];  // F2TS[m][j] = F2[j][m]
            __syncthreads();

#pragma unroll 1
            for (int m4 = 0; m4 < 32; ++m4) {
                const int mm = m4 << 2;
                f4 ft0 = *(const f4*)&F2TS[(mm + 0) * 132 + cq];
                f4 ft1 = *(const f4*)&F2TS[(mm + 1) * 132 + cq];
                f4 ft2 = *(const f4*)&F2TS[(mm + 2) * 132 + cq];
                f4 ft3 = *(const f4*)&F2TS[(mm + 3) * 132 + cq];
#pragma unroll
                for (int r = 0; r < 8; ++r) {
                    f4 x = *(const f4*)&XS[(r0 + r) * 132 + mm];
                    Yv[r] += ft0 * x[0];
                    Yv[r] += ft1 * x[1];
                    Yv[r] += ft2 * x[2];
                    Yv[r] += ft3 * x[3];
                }
            }

            // Cv += F1^T * Y2, kt-tiled: F1T[i][k'] = F1[kt*32+k'][i]
#pragma unroll 1
            for (int kt = 0; kt < 4; ++kt) {
                __syncthreads();
                if ((ww >> 2) == kt) {
#pragma unroll
                    for (int r = 0; r < 8; ++r)
                        *(f4*)&YT[(((ww & 3) << 3) + r) * 128 + cq] = Yv[r];
                }
                for (int e = tid; e < 4096; e += NTHR)
                    F1T[(e & 127) * 36 + (e >> 7)] =
                        F1p[((kt << 5) + (e >> 7)) * 128 + (e & 127)];
                __syncthreads();

#pragma unroll 1
                for (int k4 = 0; k4 < 8; ++k4) {
                    f4 y0 = *(const f4*)&YT[(k4 * 4 + 0) * 128 + cq];
                    f4 y1 = *(const f4*)&YT[(k4 * 4 + 1) * 128 + cq];
                    f4 y2 = *(const f4*)&YT[(k4 * 4 + 2) * 128 + cq];
                    f4 y3 = *(const f4*)&YT[(k4 * 4 + 3) * 128 + cq];
#pragma unroll
                    for (int r = 0; r < 8; ++r) {
                        f4 a = *(const f4*)&F1T[(r0 + r) * 36 + (k4 << 2)];
                        Cv[r] += y0 * a[0];
                        Cv[r] += y1 * a[1];
                        Cv[r] += y2 * a[2];
                        Cv[r] += y3 * a[3];
                    }
                }
            }
        }

        // ---------------- norm = max|C|, Xe = exp2(C * 10*log2(e)/norm) ----------------
        float mx = 0.f;
#pragma unroll
        for (int r = 0; r < 8; ++r) {
            mx = fmaxf(mx, fabsf(Cv[r][0]));
            mx = fmaxf(mx, fabsf(Cv[r][1]));
            mx = fmaxf(mx, fabsf(Cv[r][2]));
            mx = fmaxf(mx, fabsf(Cv[r][3]));
        }
#pragma unroll
        for (int off = 1; off < 64; off <<= 1)
            mx = fmaxf(mx, __shfl_xor(mx, off, 64));
        if ((tid & 63) == 0) wred[tid >> 6] = mx;
        __syncthreads();   // also separates F1/Y tile reads from ES overwrite
        float nrm = wred[0];
#pragma unroll
        for (int u = 1; u < 8; ++u) nrm = fmaxf(nrm, wred[u]);
        const float se = 14.426950408889634f / nrm;  // 10*log2(e)/norm

#pragma unroll
        for (int r = 0; r < 8; ++r) {
            f4 ev;
            ev[0] = exp2f(Cv[r][0] * se);
            ev[1] = exp2f(Cv[r][1] * se);
            ev[2] = exp2f(Cv[r][2] * se);
            ev[3] = exp2f(Cv[r][3] * se);
            *(f4*)&ES[(r0 + r) * 132 + cq] = ev;
        }
        if (tid < 128) rvS[tid] = 1.0f;
        __syncthreads();

        // register copies: xer = row si (cols sq*32..+32); xec = col si (rows sq*32..+32)
        f4 xer[8];
        float xec[32];
#pragma unroll
        for (int u = 0; u < 8; ++u)
            xer[u] = *(const f4*)&ES[si * 132 + sq * 32 + u * 4];
#pragma unroll
        for (int ii = 0; ii < 32; ++ii)
            xec[ii] = ES[(sq * 32 + ii) * 132 + si];

        // ---------------- Sinkhorn: lu = 1/(Xe rv); rv = min(1/(Xe^T lu), 1) ----------------
        float lu = 0.f;
#pragma unroll 1
        for (int sit = 0; sit < 15; ++sit) {
            f4 s4 = {0.f, 0.f, 0.f, 0.f};
#pragma unroll
            for (int u = 0; u < 8; ++u) {
                f4 rv4 = *(const f4*)&rvS[sq * 32 + u * 4];
                s4 += xer[u] * rv4;
            }
            float s = (s4[0] + s4[1]) + (s4[2] + s4[3]);
            s += __shfl_xor(s, 1, 64);
            s += __shfl_xor(s, 2, 64);
            lu = 1.0f / s;
            if (sq == 0) luS[si] = lu;
            __syncthreads();

            f4 t4 = {0.f, 0.f, 0.f, 0.f};
#pragma unroll
            for (int u = 0; u < 8; ++u) {
                f4 lu4 = *(const f4*)&luS[sq * 32 + u * 4];
                f4 xc4 = { xec[u*4+0], xec[u*4+1], xec[u*4+2], xec[u*4+3] };
                t4 += xc4 * lu4;
            }
            float s2 = (t4[0] + t4[1]) + (t4[2] + t4[3]);
            s2 += __shfl_xor(s2, 1, 64);
            s2 += __shfl_xor(s2, 2, 64);
            float rv = fminf(1.0f / s2, 1.0f);
            if (sq == 0) rvS[si] = rv;
            __syncthreads();
        }

        // ---------------- X = lu * Xe * rv^T ----------------
        if (it < 14) {
#pragma unroll
            for (int u = 0; u < 8; ++u) {
                f4 rv4 = *(const f4*)&rvS[sq * 32 + u * 4];
                f4 xv = xer[u] * lu * rv4;
                *(f4*)&XS[si * 132 + sq * 32 + u * 4] = xv;
            }
        } else {
#pragma unroll
            for (int u = 0; u < 8; ++u) {
                f4 rv4 = *(const f4*)&rvS[sq * 32 + u * 4];
                f4 xv = xer[u] * lu * rv4;
                *(f4*)&Op[si * 128 + sq * 32 + u * 4] = xv;
            }
        }
        __syncthreads();
    }
}

extern "C" void kernel_launch(void* const* d_in, const int* in_sizes, int n_in,
                              void* d_out, int out_size, void* d_ws, size_t ws_size,
                              hipStream_t stream) {
    const float* X  = (const float*)d_in[0];
    const float* F1 = (const float*)d_in[1];
    const float* F2 = (const float*)d_in[2];
    const float* Kp = (const float*)d_in[3];
    float* out = (float*)d_out;
    int bs = in_sizes[0] >> 14;  // elements / (128*128)
    gw32<<<bs, NTHR, 0, stream>>>(X, F1, F2, Kp, out);
}